// Round 5
// baseline (879.279 us; speedup 1.0000x reference)
//
#include <hip/hip_runtime.h>

#define BATCH 64
#define TT    1024
#define INC   16
#define NN    512
#define RNK   16
#define OUTC  8
#define BT    (BATCH * TT)

// a = DT/TAU = 0.1
#define A_COEF 0.1f

__device__ __forceinline__ float fast_tanh(float x) {
    // tanh(x) = 1 - 2/(exp(2x)+1); safe at +/-inf
    float e = __expf(2.0f * x);
    return 1.0f - __fdividef(2.0f, e + 1.0f);
}

// Barrier with LDS ordering only (does NOT drain vmcnt: h stores are
// fire-and-forget, and Inp prefetch loads are waited at their use).
__device__ __forceinline__ void lgkm_barrier() {
    asm volatile("s_waitcnt lgkmcnt(0)\n\ts_barrier" ::: "memory");
}

// ---- DPP cross-lane adds (VALU pipe) ----
template<int CTRL>
__device__ __forceinline__ float dpp_add(float x) {
    int y = __builtin_amdgcn_update_dpp(0, __float_as_int(x), CTRL, 0xF, 0xF, true);
    return x + __int_as_float(y);
}

// Full 64-lane sum; result valid in lane 63. (validated R4)
__device__ __forceinline__ float wave_sum(float x) {
    x = dpp_add<0x111>(x);  // row_shr:1
    x = dpp_add<0x112>(x);  // row_shr:2
    x = dpp_add<0x114>(x);  // row_shr:4
    x = dpp_add<0x118>(x);  // row_shr:8
    x = dpp_add<0x142>(x);  // row_bcast15
    x = dpp_add<0x143>(x);  // row_bcast31 -> total at lane 63
    return x;
}

// ============ Kernel 1: Inp[bt,n] = sum_i x[bt,i] * In_w[n,i] ============
// Fully parallel, memory-bound (~134 MB write). Grid: BT/32 blocks x 512 thr.
__global__ __launch_bounds__(512) void inp_kernel(
    const float* __restrict__ x,      // [BT, INC]
    const float* __restrict__ In_w,   // [NN, INC]
    float* __restrict__ Inp)          // [BT, NN]
{
    const int n = threadIdx.x;
    const int row0 = blockIdx.x * 32;

    float W[INC];
    #pragma unroll
    for (int k = 0; k < 4; ++k) {
        float4 w = *(const float4*)&In_w[n * INC + k * 4];
        W[k*4+0] = w.x; W[k*4+1] = w.y; W[k*4+2] = w.z; W[k*4+3] = w.w;
    }

    #pragma unroll 4
    for (int r = 0; r < 32; ++r) {
        const int row = row0 + r;
        const float4* xr = (const float4*)(x + (size_t)row * INC);
        float4 a = xr[0], bq = xr[1], c = xr[2], d = xr[3];
        float s0 = W[0]  * a.x;
        float s1 = W[1]  * a.y;
        float s2 = W[2]  * a.z;
        float s3 = W[3]  * a.w;
        s0 = fmaf(W[4],  bq.x, s0);
        s1 = fmaf(W[5],  bq.y, s1);
        s2 = fmaf(W[6],  bq.z, s2);
        s3 = fmaf(W[7],  bq.w, s3);
        s0 = fmaf(W[8],  c.x, s0);
        s1 = fmaf(W[9],  c.y, s1);
        s2 = fmaf(W[10], c.z, s2);
        s3 = fmaf(W[11], c.w, s3);
        s0 = fmaf(W[12], d.x, s0);
        s1 = fmaf(W[13], d.y, s1);
        s2 = fmaf(W[14], d.z, s2);
        s3 = fmaf(W[15], d.w, s3);
        Inp[(size_t)row * NN + n] = (s0 + s1) + (s2 + s3);
    }
}

// ============ Kernel 2: the scan ============
// One block per batch. 512 threads = 8 waves; lane owns state n = tid.
// Wave w owns low-rank rows r = 2w, 2w+1: phi read is 2 conflict-free
// natural-stride ds_read_b128 per wave; reduce via DPP; low via 16-float LDS.
__global__ __launch_bounds__(512, 1) void scan_kernel(
    const float* __restrict__ Inp,    // [BT, NN] precomputed input projection
    const float* __restrict__ V_w,    // [RNK, NN]
    const float* __restrict__ U_w,    // [NN, RNK]
    const float* __restrict__ h0,     // [NN]
    float* __restrict__ hidden)       // [BATCH, TT, NN]
{
    const int b   = blockIdx.x;
    const int tid = threadIdx.x;
    const int w   = tid >> 6;   // wave id: owns r = 2w, 2w+1
    const int p   = tid & 63;   // lane within wave

    __shared__ __align__(16) float phi_s[NN];
    __shared__ __align__(16) float low_s[RNK];

    // U row for this lane's n
    float Ur[RNK];
    #pragma unroll
    for (int k = 0; k < 4; ++k) {
        float4 u = *(const float4*)&U_w[tid * RNK + k * 4];
        Ur[k*4+0] = u.x; Ur[k*4+1] = u.y; Ur[k*4+2] = u.z; Ur[k*4+3] = u.w;
    }

    // V fragments: lane p covers n = 4p+k (j=0) and 256+4p+k (j=1)
    float Va[8], Vb[8];
    #pragma unroll
    for (int j = 0; j < 2; ++j) {
        float4 va = *(const float4*)&V_w[(2*w)   * NN + j * 256 + 4 * p];
        float4 vb = *(const float4*)&V_w[(2*w+1) * NN + j * 256 + 4 * p];
        Va[j*4+0] = va.x; Va[j*4+1] = va.y; Va[j*4+2] = va.z; Va[j*4+3] = va.w;
        Vb[j*4+0] = vb.x; Vb[j*4+1] = vb.y; Vb[j*4+2] = vb.z; Vb[j*4+3] = vb.w;
    }

    float h = h0[tid];

    const float* ib = Inp + (size_t)b * TT * NN + tid;
    float* hb = hidden + (size_t)b * TT * NN + tid;

    // prefetch Inp for t=0,1
    float inp_c = ib[0];
    float inp_n = ib[NN];

    __syncthreads();  // weights + initial loads settled

    for (int t = 0; t < TT; ++t) {
        float phi = fast_tanh(h);
        phi_s[tid] = phi;            // b32, conflict-free

        lgkm_barrier();              // phi visible

        // conflict-free natural-stride reads: lane p -> phi[4p], phi[256+4p]
        float4 ph0 = *(const float4*)&phi_s[4 * p];
        float4 ph1 = *(const float4*)&phi_s[256 + 4 * p];

        float pa0 = Va[0] * ph0.x;
        float pa1 = Va[1] * ph0.y;
        float pb0 = Vb[0] * ph0.x;
        float pb1 = Vb[1] * ph0.y;
        pa0 = fmaf(Va[2], ph0.z, pa0);
        pa1 = fmaf(Va[3], ph0.w, pa1);
        pb0 = fmaf(Vb[2], ph0.z, pb0);
        pb1 = fmaf(Vb[3], ph0.w, pb1);
        pa0 = fmaf(Va[4], ph1.x, pa0);
        pa1 = fmaf(Va[5], ph1.y, pa1);
        pb0 = fmaf(Vb[4], ph1.x, pb0);
        pb1 = fmaf(Vb[5], ph1.y, pb1);
        pa0 = fmaf(Va[6], ph1.z, pa0);
        pa1 = fmaf(Va[7], ph1.w, pa1);
        pb0 = fmaf(Vb[6], ph1.z, pb0);
        pb1 = fmaf(Vb[7], ph1.w, pb1);
        float pa = wave_sum(pa0 + pa1);   // two independent DPP chains
        float pb = wave_sum(pb0 + pb1);
        if (p == 63)
            *(float2*)&low_s[2 * w] = make_float2(pa, pb);

        // prefetch Inp for t+2 (VMEM; L3-resident; waited at use next iter)
        int tn = (t + 2 < TT) ? t + 2 : TT - 1;
        float inp_f = ib[(size_t)tn * NN];

        lgkm_barrier();              // low visible

        // rec = U[n,:] . low  (same-address broadcast reads)
        float4 l0 = *(const float4*)&low_s[0];
        float4 l1 = *(const float4*)&low_s[4];
        float4 l2 = *(const float4*)&low_s[8];
        float4 l3 = *(const float4*)&low_s[12];
        float ra = Ur[0] * l0.x;
        float rb = Ur[1] * l0.y;
        float rc = Ur[2] * l0.z;
        float rd = Ur[3] * l0.w;
        ra = fmaf(Ur[4],  l1.x, ra);
        rb = fmaf(Ur[5],  l1.y, rb);
        rc = fmaf(Ur[6],  l1.z, rc);
        rd = fmaf(Ur[7],  l1.w, rd);
        ra = fmaf(Ur[8],  l2.x, ra);
        rb = fmaf(Ur[9],  l2.y, rb);
        rc = fmaf(Ur[10], l2.z, rc);
        rd = fmaf(Ur[11], l2.w, rd);
        ra = fmaf(Ur[12], l3.x, ra);
        rb = fmaf(Ur[13], l3.y, rb);
        rc = fmaf(Ur[14], l3.z, rc);
        rd = fmaf(Ur[15], l3.w, rd);
        float rec = (ra + rb) + (rc + rd);

        h = fmaf(A_COEF, (rec + inp_c) - h, h);   // (1-a)h + a(rec+inp)
        hb[(size_t)t * NN] = h;                   // fire-and-forget

        inp_c = inp_n;
        inp_n = inp_f;
    }
}

// ============ Kernel 3: out[bt,o] = sum_n Out_w[o,n] * tanh(hidden[bt,n]) ====
// One wave per row-slice; DPP-only reduction (no LDS). Memory-bound (~134 MB).
__global__ __launch_bounds__(256) void out_kernel(
    const float* __restrict__ hidden,  // [BT, NN]
    const float* __restrict__ Out_w,   // [OUTC, NN]
    float* __restrict__ out)           // [BT, OUTC]
{
    const int lane = threadIdx.x & 63;
    const int wv   = threadIdx.x >> 6;
    const int gw   = blockIdx.x * 4 + wv;   // 512 blocks * 4 waves = 2048 waves

    // lane covers n = lane*8 .. lane*8+7 for all 8 outputs
    float Ow[OUTC][8];
    #pragma unroll
    for (int o = 0; o < OUTC; ++o) {
        float4 w0 = *(const float4*)&Out_w[o * NN + lane * 8];
        float4 w1 = *(const float4*)&Out_w[o * NN + lane * 8 + 4];
        Ow[o][0] = w0.x; Ow[o][1] = w0.y; Ow[o][2] = w0.z; Ow[o][3] = w0.w;
        Ow[o][4] = w1.x; Ow[o][5] = w1.y; Ow[o][6] = w1.z; Ow[o][7] = w1.w;
    }

    #pragma unroll 2
    for (int rr = 0; rr < 32; ++rr) {
        const int row = gw * 32 + rr;
        const float* hr = hidden + (size_t)row * NN + lane * 8;
        float4 a0 = *(const float4*)&hr[0];
        float4 a1 = *(const float4*)&hr[4];
        float ph[8];
        ph[0] = fast_tanh(a0.x); ph[1] = fast_tanh(a0.y);
        ph[2] = fast_tanh(a0.z); ph[3] = fast_tanh(a0.w);
        ph[4] = fast_tanh(a1.x); ph[5] = fast_tanh(a1.y);
        ph[6] = fast_tanh(a1.z); ph[7] = fast_tanh(a1.w);

        float acc[OUTC];
        #pragma unroll
        for (int o = 0; o < OUTC; ++o) {
            float s = Ow[o][0] * ph[0];
            #pragma unroll
            for (int j = 1; j < 8; ++j) s = fmaf(Ow[o][j], ph[j], s);
            acc[o] = wave_sum(s);   // valid at lane 63; 8 chains interleave
        }
        if (lane == 63) {
            float4 r0 = make_float4(acc[0], acc[1], acc[2], acc[3]);
            float4 r1 = make_float4(acc[4], acc[5], acc[6], acc[7]);
            *(float4*)&out[(size_t)row * OUTC]     = r0;
            *(float4*)&out[(size_t)row * OUTC + 4] = r1;
        }
    }
}

extern "C" void kernel_launch(void* const* d_in, const int* in_sizes, int n_in,
                              void* d_out, int out_size, void* d_ws, size_t ws_size,
                              hipStream_t stream) {
    const float* x    = (const float*)d_in[0];  // [64,1024,16]
    const float* In_w = (const float*)d_in[1];  // [512,16]
    const float* V_w  = (const float*)d_in[2];  // [16,512]
    const float* U_w  = (const float*)d_in[3];  // [512,16]
    const float* Ow   = (const float*)d_in[4];  // [8,512]
    const float* h0   = (const float*)d_in[5];  // [512]

    float* hidden = (float*)d_out;                         // [64,1024,512]
    float* out    = hidden + (size_t)BATCH * TT * NN;      // [64,1024,8]
    float* Inp    = (float*)d_ws;                          // [BT, NN] = 134 MB

    inp_kernel<<<BT / 32, 512, 0, stream>>>(x, In_w, Inp);
    scan_kernel<<<BATCH, 512, 0, stream>>>(Inp, V_w, U_w, h0, hidden);
    out_kernel<<<512, 256, 0, stream>>>(hidden, Ow, out);
}

// Round 6
// 871.726 us; speedup vs baseline: 1.0087x; 1.0087x over previous
//
#include <hip/hip_runtime.h>

#define BATCH 64
#define TT    1024
#define INC   16
#define NN    512
#define RNK   16
#define OUTC  8

// a = DT/TAU = 0.1
#define A_COEF 0.1f

__device__ __forceinline__ float fast_tanh(float x) {
    // tanh(x) = 1 - 2/(exp(2x)+1); safe at +/-inf
    float e = __expf(2.0f * x);
    return 1.0f - __fdividef(2.0f, e + 1.0f);
}

// Barrier with LDS ordering only (does NOT drain vmcnt: h/out stores are
// fire-and-forget, never read in-kernel).
__device__ __forceinline__ void lgkm_barrier() {
    asm volatile("s_waitcnt lgkmcnt(0)\n\ts_barrier" ::: "memory");
}

// ---- DPP cross-lane ops (VALU pipe) ----
template<int CTRL>
__device__ __forceinline__ float dpp_add(float x) {
    int y = __builtin_amdgcn_update_dpp(0, __float_as_int(x), CTRL, 0xF, 0xF, true);
    return x + __int_as_float(y);
}

// Full 64-lane sum; result valid in lane 63. (validated R4/R5)
__device__ __forceinline__ float wave_sum(float x) {
    x = dpp_add<0x111>(x);  // row_shr:1
    x = dpp_add<0x112>(x);  // row_shr:2
    x = dpp_add<0x114>(x);  // row_shr:4
    x = dpp_add<0x118>(x);  // row_shr:8
    x = dpp_add<0x142>(x);  // row_bcast15
    x = dpp_add<0x143>(x);  // row_bcast31 -> total at lane 63
    return x;
}

// quad_perm broadcast of quad-lane K to all 4 lanes of each quad.
template<int K>
__device__ __forceinline__ float quad_bcast(float x) {
    constexpr int ctrl = K * 0x55;  // K | K<<2 | K<<4 | K<<6
    int y = __builtin_amdgcn_update_dpp(0, __float_as_int(x), ctrl, 0xF, 0xF, true);
    return __int_as_float(y);
}

// One block per batch. 256 threads = 4 waves (1 wave/SIMD).
// Lane owns states n0 = tid, n1 = tid+256. Wave w owns low-rank rows 4w..4w+3
// and outputs 2w, 2w+1. All weights in registers; phi/low via LDS with
// lgkm-only barriers; reductions via DPP; low re-broadcast via quad_perm.
__global__ __launch_bounds__(256, 1) void scan_kernel(
    const float* __restrict__ x,      // [B,T,INC]
    const float* __restrict__ In_w,   // [N,INC]
    const float* __restrict__ V_w,    // [R,N]
    const float* __restrict__ U_w,    // [N,R]
    const float* __restrict__ Out_w,  // [OUTC,N]
    const float* __restrict__ h0,     // [N]
    float* __restrict__ hidden,       // [B,T,N]
    float* __restrict__ out)          // [B,T,OUTC]
{
    const int b   = blockIdx.x;
    const int tid = threadIdx.x;
    const int w   = tid >> 6;   // wave id 0..3
    const int p   = tid & 63;   // lane in wave
    const int q   = p & 3;      // quad position (low read split)

    __shared__ __align__(16) float xs[TT * INC];  // 64 KB: whole x[b]
    __shared__ __align__(16) float phi_s[NN];
    __shared__ __align__(16) float low_s[RNK];

    // ---- stage x[b] (64 KB) into LDS, coalesced float4 ----
    {
        const float4* src = (const float4*)(x + (size_t)b * TT * INC);
        float4* dst = (float4*)xs;
        #pragma unroll
        for (int c = 0; c < 16; ++c)
            dst[c * 256 + tid] = src[c * 256 + tid];
    }

    // ---- per-lane weights in registers ----
    // U rows for n0, n1
    float U0[RNK], U1[RNK];
    #pragma unroll
    for (int k = 0; k < 4; ++k) {
        float4 u = *(const float4*)&U_w[tid * RNK + k * 4];
        U0[k*4+0] = u.x; U0[k*4+1] = u.y; U0[k*4+2] = u.z; U0[k*4+3] = u.w;
        float4 v = *(const float4*)&U_w[(tid + 256) * RNK + k * 4];
        U1[k*4+0] = v.x; U1[k*4+1] = v.y; U1[k*4+2] = v.z; U1[k*4+3] = v.w;
    }
    // In_w rows for n0, n1
    float W0[INC], W1[INC];
    #pragma unroll
    for (int k = 0; k < 4; ++k) {
        float4 a = *(const float4*)&In_w[tid * INC + k * 4];
        W0[k*4+0] = a.x; W0[k*4+1] = a.y; W0[k*4+2] = a.z; W0[k*4+3] = a.w;
        float4 c = *(const float4*)&In_w[(tid + 256) * INC + k * 4];
        W1[k*4+0] = c.x; W1[k*4+1] = c.y; W1[k*4+2] = c.z; W1[k*4+3] = c.w;
    }
    // V fragments: rows r = 4w+rr; lane p covers n = 4p+j and 256+4p+j
    float V[4][8];
    #pragma unroll
    for (int rr = 0; rr < 4; ++rr) {
        const int r = 4 * w + rr;
        float4 va = *(const float4*)&V_w[r * NN + 4 * p];
        float4 vb = *(const float4*)&V_w[r * NN + 256 + 4 * p];
        V[rr][0] = va.x; V[rr][1] = va.y; V[rr][2] = va.z; V[rr][3] = va.w;
        V[rr][4] = vb.x; V[rr][5] = vb.y; V[rr][6] = vb.z; V[rr][7] = vb.w;
    }
    // Out_w fragments: outputs o = 2w, 2w+1; same phi coverage as V
    float O0[8], O1[8];
    {
        float4 a = *(const float4*)&Out_w[(2*w) * NN + 4 * p];
        float4 c = *(const float4*)&Out_w[(2*w) * NN + 256 + 4 * p];
        O0[0]=a.x; O0[1]=a.y; O0[2]=a.z; O0[3]=a.w;
        O0[4]=c.x; O0[5]=c.y; O0[6]=c.z; O0[7]=c.w;
        float4 d = *(const float4*)&Out_w[(2*w+1) * NN + 4 * p];
        float4 e = *(const float4*)&Out_w[(2*w+1) * NN + 256 + 4 * p];
        O1[0]=d.x; O1[1]=d.y; O1[2]=d.z; O1[3]=d.w;
        O1[4]=e.x; O1[5]=e.y; O1[6]=e.z; O1[7]=e.w;
    }

    float h0v = h0[tid];
    float h1v = h0[tid + 256];

    __syncthreads();  // staging + weights settled (full drain, once)

    float* hb = hidden + (size_t)b * TT * NN;
    float* ob = out + (size_t)b * TT * OUTC;

    // x for t=0 (broadcast reads from LDS)
    float4 xc0, xc1, xc2, xc3;
    {
        const float4* xp = (const float4*)xs;
        xc0 = xp[0]; xc1 = xp[1]; xc2 = xp[2]; xc3 = xp[3];
    }

    for (int t = 0; t < TT; ++t) {
        // ---- phase A: tanh + phi publish + input projection ----
        float phi0 = fast_tanh(h0v);
        float phi1 = fast_tanh(h1v);
        phi_s[tid]       = phi0;
        phi_s[tid + 256] = phi1;

        float i0a = W0[0]  * xc0.x,  i0b = W0[1]  * xc0.y;
        float i0c = W0[2]  * xc0.z,  i0d = W0[3]  * xc0.w;
        float i1a = W1[0]  * xc0.x,  i1b = W1[1]  * xc0.y;
        float i1c = W1[2]  * xc0.z,  i1d = W1[3]  * xc0.w;
        i0a = fmaf(W0[4],  xc1.x, i0a);  i0b = fmaf(W0[5],  xc1.y, i0b);
        i0c = fmaf(W0[6],  xc1.z, i0c);  i0d = fmaf(W0[7],  xc1.w, i0d);
        i1a = fmaf(W1[4],  xc1.x, i1a);  i1b = fmaf(W1[5],  xc1.y, i1b);
        i1c = fmaf(W1[6],  xc1.z, i1c);  i1d = fmaf(W1[7],  xc1.w, i1d);
        i0a = fmaf(W0[8],  xc2.x, i0a);  i0b = fmaf(W0[9],  xc2.y, i0b);
        i0c = fmaf(W0[10], xc2.z, i0c);  i0d = fmaf(W0[11], xc2.w, i0d);
        i1a = fmaf(W1[8],  xc2.x, i1a);  i1b = fmaf(W1[9],  xc2.y, i1b);
        i1c = fmaf(W1[10], xc2.z, i1c);  i1d = fmaf(W1[11], xc2.w, i1d);
        i0a = fmaf(W0[12], xc3.x, i0a);  i0b = fmaf(W0[13], xc3.y, i0b);
        i0c = fmaf(W0[14], xc3.z, i0c);  i0d = fmaf(W0[15], xc3.w, i0d);
        i1a = fmaf(W1[12], xc3.x, i1a);  i1b = fmaf(W1[13], xc3.y, i1b);
        i1c = fmaf(W1[14], xc3.z, i1c);  i1d = fmaf(W1[15], xc3.w, i1d);
        float inp0 = (i0a + i0b) + (i0c + i0d);
        float inp1 = (i1a + i1b) + (i1c + i1d);

        lgkm_barrier();   // phi visible

        // ---- phase B: V partials + out partials (same phi regs) ----
        float4 ph0 = *(const float4*)&phi_s[4 * p];         // conflict-free
        float4 ph1 = *(const float4*)&phi_s[256 + 4 * p];

        float pr[4];
        #pragma unroll
        for (int rr = 0; rr < 4; ++rr) {
            float a = V[rr][0] * ph0.x;
            float bq = V[rr][1] * ph0.y;
            a  = fmaf(V[rr][2], ph0.z, a);
            bq = fmaf(V[rr][3], ph0.w, bq);
            a  = fmaf(V[rr][4], ph1.x, a);
            bq = fmaf(V[rr][5], ph1.y, bq);
            a  = fmaf(V[rr][6], ph1.z, a);
            bq = fmaf(V[rr][7], ph1.w, bq);
            pr[rr] = a + bq;
        }
        // 4 independent DPP chains interleave
        pr[0] = wave_sum(pr[0]);
        pr[1] = wave_sum(pr[1]);
        pr[2] = wave_sum(pr[2]);
        pr[3] = wave_sum(pr[3]);
        if (p == 63)
            *(float4*)&low_s[4 * w] = make_float4(pr[0], pr[1], pr[2], pr[3]);

        // out partials for o = 2w, 2w+1 (lane-local phi, zero extra LDS)
        float oa = O0[0] * ph0.x;
        float obq = O0[1] * ph0.y;
        oa  = fmaf(O0[2], ph0.z, oa);
        obq = fmaf(O0[3], ph0.w, obq);
        oa  = fmaf(O0[4], ph1.x, oa);
        obq = fmaf(O0[5], ph1.y, obq);
        oa  = fmaf(O0[6], ph1.z, oa);
        obq = fmaf(O0[7], ph1.w, obq);
        float os0 = wave_sum(oa + obq);
        float ca = O1[0] * ph0.x;
        float cb = O1[1] * ph0.y;
        ca = fmaf(O1[2], ph0.z, ca);
        cb = fmaf(O1[3], ph0.w, cb);
        ca = fmaf(O1[4], ph1.x, ca);
        cb = fmaf(O1[5], ph1.y, cb);
        ca = fmaf(O1[6], ph1.z, ca);
        cb = fmaf(O1[7], ph1.w, cb);
        float os1 = wave_sum(ca + cb);
        // phi here = tanh(h_{t-1}) -> this is out[b, t-1, :]
        if (t > 0 && p == 63)
            *(float2*)&ob[(t - 1) * OUTC + 2 * w] = make_float2(os0, os1);

        // prefetch x(t+1) (broadcast LDS read, consumed next iter)
        {
            int tn = (t + 1 < TT) ? t + 1 : t;
            const float4* xp = (const float4*)(xs + tn * INC);
            xc0 = xp[0]; xc1 = xp[1]; xc2 = xp[2]; xc3 = xp[3];
        }

        lgkm_barrier();   // low visible

        // ---- phase C: quad-split low read + quad_perm gather + rec ----
        float4 L = *(const float4*)&low_s[4 * q];   // lane reads its quarter
        float Lg[16];
        Lg[0]  = quad_bcast<0>(L.x);  Lg[1]  = quad_bcast<0>(L.y);
        Lg[2]  = quad_bcast<0>(L.z);  Lg[3]  = quad_bcast<0>(L.w);
        Lg[4]  = quad_bcast<1>(L.x);  Lg[5]  = quad_bcast<1>(L.y);
        Lg[6]  = quad_bcast<1>(L.z);  Lg[7]  = quad_bcast<1>(L.w);
        Lg[8]  = quad_bcast<2>(L.x);  Lg[9]  = quad_bcast<2>(L.y);
        Lg[10] = quad_bcast<2>(L.z);  Lg[11] = quad_bcast<2>(L.w);
        Lg[12] = quad_bcast<3>(L.x);  Lg[13] = quad_bcast<3>(L.y);
        Lg[14] = quad_bcast<3>(L.z);  Lg[15] = quad_bcast<3>(L.w);

        float r0a = U0[0] * Lg[0],  r0b = U0[1] * Lg[1];
        float r0c = U0[2] * Lg[2],  r0d = U0[3] * Lg[3];
        float r1a = U1[0] * Lg[0],  r1b = U1[1] * Lg[1];
        float r1c = U1[2] * Lg[2],  r1d = U1[3] * Lg[3];
        #pragma unroll
        for (int k = 1; k < 4; ++k) {
            r0a = fmaf(U0[4*k+0], Lg[4*k+0], r0a);
            r0b = fmaf(U0[4*k+1], Lg[4*k+1], r0b);
            r0c = fmaf(U0[4*k+2], Lg[4*k+2], r0c);
            r0d = fmaf(U0[4*k+3], Lg[4*k+3], r0d);
            r1a = fmaf(U1[4*k+0], Lg[4*k+0], r1a);
            r1b = fmaf(U1[4*k+1], Lg[4*k+1], r1b);
            r1c = fmaf(U1[4*k+2], Lg[4*k+2], r1c);
            r1d = fmaf(U1[4*k+3], Lg[4*k+3], r1d);
        }
        float rec0 = (r0a + r0b) + (r0c + r0d);
        float rec1 = (r1a + r1b) + (r1c + r1d);

        h0v = fmaf(A_COEF, (rec0 + inp0) - h0v, h0v);
        h1v = fmaf(A_COEF, (rec1 + inp1) - h1v, h1v);
        hb[t * NN + tid]       = h0v;   // fire-and-forget
        hb[t * NN + tid + 256] = h1v;
    }

    // ---- epilogue: out[b, TT-1, :] from tanh of final h ----
    float phi0 = fast_tanh(h0v);
    float phi1 = fast_tanh(h1v);
    phi_s[tid]       = phi0;
    phi_s[tid + 256] = phi1;
    lgkm_barrier();
    {
        float4 ph0 = *(const float4*)&phi_s[4 * p];
        float4 ph1 = *(const float4*)&phi_s[256 + 4 * p];
        float oa = O0[0] * ph0.x;
        float obq = O0[1] * ph0.y;
        oa  = fmaf(O0[2], ph0.z, oa);
        obq = fmaf(O0[3], ph0.w, obq);
        oa  = fmaf(O0[4], ph1.x, oa);
        obq = fmaf(O0[5], ph1.y, obq);
        oa  = fmaf(O0[6], ph1.z, oa);
        obq = fmaf(O0[7], ph1.w, obq);
        float os0 = wave_sum(oa + obq);
        float ca = O1[0] * ph0.x;
        float cb = O1[1] * ph0.y;
        ca = fmaf(O1[2], ph0.z, ca);
        cb = fmaf(O1[3], ph0.w, cb);
        ca = fmaf(O1[4], ph1.x, ca);
        cb = fmaf(O1[5], ph1.y, cb);
        ca = fmaf(O1[6], ph1.z, ca);
        cb = fmaf(O1[7], ph1.w, cb);
        float os1 = wave_sum(ca + cb);
        if (p == 63)
            *(float2*)&ob[(TT - 1) * OUTC + 2 * w] = make_float2(os0, os1);
    }
}

extern "C" void kernel_launch(void* const* d_in, const int* in_sizes, int n_in,
                              void* d_out, int out_size, void* d_ws, size_t ws_size,
                              hipStream_t stream) {
    const float* x    = (const float*)d_in[0];  // [64,1024,16]
    const float* In_w = (const float*)d_in[1];  // [512,16]
    const float* V_w  = (const float*)d_in[2];  // [16,512]
    const float* U_w  = (const float*)d_in[3];  // [512,16]
    const float* Ow   = (const float*)d_in[4];  // [8,512]
    const float* h0   = (const float*)d_in[5];  // [512]

    float* hidden = (float*)d_out;                         // [64,1024,512]
    float* out    = hidden + (size_t)BATCH * TT * NN;      // [64,1024,8]

    scan_kernel<<<BATCH, 256, 0, stream>>>(x, In_w, V_w, U_w, Ow, h0, hidden, out);
}